// Round 1
// baseline (370.946 us; speedup 1.0000x reference)
//
#include <hip/hip_runtime.h>
#include <cstdint>
#include <cstddef>

#define HID 128
#define DIM 64
#define ROWS 16
#define TMAIN 512

typedef float f32x4 __attribute__((ext_vector_type(4)));
typedef short s16x8 __attribute__((ext_vector_type(8)));

__device__ __forceinline__ unsigned short f2bf(float x){
    union { float f; unsigned int u; } v; v.f = x;
    unsigned int r = v.u + 0x7FFFu + ((v.u >> 16) & 1u);
    return (unsigned short)(r >> 16);
}
__device__ __forceinline__ float bf2f(unsigned short b){
    union { unsigned int u; float f; } v; v.u = ((unsigned int)b) << 16;
    return v.f;
}

// workspace layout (bytes)
#define WS_MINV 0
#define WS_MHI  16384
#define WS_MLO  24576
#define WS_W1   32768
#define WS_W1T  49152
#define WS_W2   65536
#define WS_W2T  98304
// total 131072 bytes of d_ws used

// ---------------- kernel 1: invert M = L L^T + 0.01 I, prep bf16 weights ----------------
__global__ __launch_bounds__(256) void k_prep(
    const float* __restrict__ L, const float* __restrict__ W1,
    const float* __restrict__ W2, char* __restrict__ ws)
{
    __shared__ float aug[64][128];
    const int tid = threadIdx.x;
    unsigned short* w1b = (unsigned short*)(ws + WS_W1);
    unsigned short* w1t = (unsigned short*)(ws + WS_W1T);
    unsigned short* w2b = (unsigned short*)(ws + WS_W2);
    unsigned short* w2t = (unsigned short*)(ws + WS_W2T);
    for (int i = tid; i < HID*DIM; i += 256){
        float v = W1[i]; unsigned short b = f2bf(v);
        w1b[i] = b; int h = i >> 6, d = i & 63; w1t[d*HID + h] = b;
    }
    for (int i = tid; i < HID*HID; i += 256){
        float v = W2[i]; unsigned short b = f2bf(v);
        w2b[i] = b; int c2 = i >> 7, c1 = i & 127; w2t[c1*HID + c2] = b;
    }
    // build augmented [M | I]
    for (int e = tid; e < 64*64; e += 256){
        int r = e >> 6, c = e & 63;
        float acc = (r == c) ? 0.01f : 0.0f;
        for (int k = 0; k < 64; ++k) acc += L[r*64+k] * L[c*64+k];
        aug[r][c] = acc;
        aug[r][64+c] = (r == c) ? 1.0f : 0.0f;
    }
    __syncthreads();
    // Gauss-Jordan, no pivoting (M is SPD, diag-dominant, cond ~ 2)
    const int r = tid >> 2, q4 = tid & 3;
    for (int k = 0; k < 64; ++k){
        float pivinv = 1.0f / aug[k][k];
        float f = aug[r][k];
        __syncthreads();
        if (r == k){
            for (int c = q4*32; c < q4*32+32; ++c) aug[k][c] *= pivinv;
        }
        __syncthreads();
        if (r != k){
            for (int c = q4*32; c < q4*32+32; ++c) aug[r][c] -= f * aug[k][c];
        }
        __syncthreads();
    }
    // write Minv f32 + hi/lo bf16 split (hi+lo keeps Minv (~50/entry) accurate)
    float* minv = (float*)(ws + WS_MINV);
    unsigned short* mhi = (unsigned short*)(ws + WS_MHI);
    unsigned short* mlo = (unsigned short*)(ws + WS_MLO);
    for (int i = tid; i < 64*64; i += 256){
        float m = aug[i >> 6][64 + (i & 63)];
        minv[i] = m;
        unsigned short h = f2bf(m);
        mhi[i] = h;
        mlo[i] = f2bf(m - bf2f(h));
    }
}

// ---------------- kernel 2: encoder q0 = z qW^T + qb, p0 = z pW^T + pb -> traj[:,0,:] ----------------
__global__ __launch_bounds__(256) void k_enc(
    const float* __restrict__ z, const float* __restrict__ qW,
    const float* __restrict__ qb, const float* __restrict__ pW,
    const float* __restrict__ pb, const int* __restrict__ nsp,
    float* __restrict__ out, int B)
{
    const int g = blockIdx.x * 256 + threadIdx.x;
    if (g >= B * 128) return;
    const int b = g >> 7, dd = g & 127, d = dd & 63;
    const float* W = (dd < 64) ? qW : pW;
    const float* bias = (dd < 64) ? qb : pb;
    const float* zr = z + (size_t)b * 64;
    const float* wr = W + d * 64;
    float acc = bias[d];
    #pragma unroll 8
    for (int k = 0; k < 64; ++k) acc += zr[k] * wr[k];
    const int NS = *nsp;
    out[(size_t)b * ((size_t)(NS+1)*128) + dd] = acc;
}

// ---------------- kernel 3: 64 leapfrog steps, 16 rows/block, MFMA 16x16x32 bf16 ----------------
__device__ __forceinline__ f32x4 mfma16(s16x8 a, s16x8 b, f32x4 c){
    return __builtin_amdgcn_mfma_f32_16x16x32_bf16(a, b, c, 0, 0, 0);
}

__global__ __launch_bounds__(TMAIN) void k_main(
    const float* __restrict__ b1, const float* __restrict__ b2,
    const float* __restrict__ w3, const int* __restrict__ nsp,
    const char* __restrict__ ws, float* __restrict__ out)
{
    // ~30 KB static LDS; activation tiles XOR-swizzled: idx ^ ((row&7)<<3)
    __shared__ __align__(16) float sb1[HID], sb2[HID], sw3v[HID];
    __shared__ __align__(16) float sQ[ROWS*DIM], sP[ROWS*DIM];
    __shared__ __align__(16) unsigned short sQb[ROWS*DIM], sPb[ROWS*DIM];
    __shared__ __align__(16) unsigned short sA1[ROWS*HID], sD1[ROWS*HID];
    __shared__ __align__(16) unsigned short sG2[ROWS*HID], sG1[ROWS*HID];

    const int tid = threadIdx.x;
    const int w = tid >> 6;
    const int lane = tid & 63;
    const int l15 = lane & 15, l4 = lane >> 4;
    const int NS = *nsp;
    const float dtv = 1.0f / (float)NS;   // T_SPAN = (0,1)
    const int TS = (NS + 1) * 128;
    const int b0 = blockIdx.x * ROWS;
    const int n0 = w * 16;

    if (tid < HID){ sb1[tid] = b1[tid]; sb2[tid] = b2[tid]; sw3v[tid] = w3[tid]; }

    // load q0/p0 written by k_enc
    for (int e = tid; e < ROWS*128; e += TMAIN){
        int row = e >> 7, dd = e & 127;
        float v = out[(size_t)(b0+row)*TS + dd];
        if (dd < 64){ sQ[row*DIM+dd] = v; sQb[(row*DIM+dd) ^ ((row&7)<<3)] = f2bf(v); }
        else        { sP[row*DIM + (dd-64)] = v; }
    }

    // persistent weight B-fragments (BT[n][k] row-major -> lane reads BT[n0+l15][kt*32+8*l4 ..+8])
    const unsigned short* wsW1  = (const unsigned short*)(ws + WS_W1);
    const unsigned short* wsW1T = (const unsigned short*)(ws + WS_W1T);
    const unsigned short* wsW2  = (const unsigned short*)(ws + WS_W2);
    const unsigned short* wsW2T = (const unsigned short*)(ws + WS_W2T);
    const unsigned short* wsMhi = (const unsigned short*)(ws + WS_MHI);
    const unsigned short* wsMlo = (const unsigned short*)(ws + WS_MLO);

    s16x8 fW1[2], fW2[4], fW2T[4];
    s16x8 fW1T[4] = {}, fMhi[2] = {}, fMlo[2] = {};
    #pragma unroll
    for (int kt = 0; kt < 2; ++kt)
        fW1[kt] = *(const s16x8*)&wsW1[(n0+l15)*DIM + kt*32 + 8*l4];
    #pragma unroll
    for (int kt = 0; kt < 4; ++kt){
        fW2[kt]  = *(const s16x8*)&wsW2 [(n0+l15)*HID + kt*32 + 8*l4];
        fW2T[kt] = *(const s16x8*)&wsW2T[(n0+l15)*HID + kt*32 + 8*l4];
    }
    if (w < 4){
        #pragma unroll
        for (int kt = 0; kt < 4; ++kt)
            fW1T[kt] = *(const s16x8*)&wsW1T[(n0+l15)*HID + kt*32 + 8*l4];
        #pragma unroll
        for (int kt = 0; kt < 2; ++kt){
            fMhi[kt] = *(const s16x8*)&wsMhi[(n0+l15)*DIM + kt*32 + 8*l4];
            fMlo[kt] = *(const s16x8*)&wsMlo[(n0+l15)*DIM + kt*32 + 8*l4];
        }
    }
    __syncthreads();

    // t=0: gradV(q0) only (half-kick init). t>=1: drift + gradV + kick, write traj[t].
    for (int t = 0; t <= NS; ++t){
        // ---- phase Q: q += dt * Minv @ p_half ; write q to traj ----
        if (t > 0){
            if (w < 4){
                f32x4 acc = {0.f,0.f,0.f,0.f};
                #pragma unroll
                for (int kt = 0; kt < 2; ++kt){
                    s16x8 aP = *(const s16x8*)&sPb[(l15*DIM + kt*32 + 8*l4) ^ ((l15&7)<<3)];
                    acc = mfma16(aP, fMhi[kt], acc);
                    acc = mfma16(aP, fMlo[kt], acc);
                }
                #pragma unroll
                for (int r = 0; r < 4; ++r){
                    int row = 4*l4 + r, dc = n0 + l15;
                    float qn = sQ[row*DIM+dc] + dtv * acc[r];
                    sQ[row*DIM+dc] = qn;
                    sQb[(row*DIM+dc) ^ ((row&7)<<3)] = f2bf(qn);
                    out[(size_t)(b0+row)*TS + (size_t)t*128 + dc] = qn;
                }
            }
            __syncthreads();
        }
        // ---- P1: h1 = q@W1^T + b1 ; a1 = silu(h1), d1 = silu'(h1) ----
        {
            f32x4 acc = {0.f,0.f,0.f,0.f};
            #pragma unroll
            for (int kt = 0; kt < 2; ++kt){
                s16x8 aQ = *(const s16x8*)&sQb[(l15*DIM + kt*32 + 8*l4) ^ ((l15&7)<<3)];
                acc = mfma16(aQ, fW1[kt], acc);
            }
            #pragma unroll
            for (int r = 0; r < 4; ++r){
                int row = 4*l4 + r, c = n0 + l15;
                float h = acc[r] + sb1[c];
                float sg = 1.0f / (1.0f + __expf(-h));
                sA1[(row*HID+c) ^ ((row&7)<<3)] = f2bf(h * sg);
                sD1[(row*HID+c) ^ ((row&7)<<3)] = f2bf(sg * (1.0f + h * (1.0f - sg)));
            }
        }
        __syncthreads();
        // ---- P2: h2 = a1@W2^T + b2 ; g2 = w3 * silu'(h2) ----
        {
            f32x4 acc = {0.f,0.f,0.f,0.f};
            #pragma unroll
            for (int kt = 0; kt < 4; ++kt){
                s16x8 aA = *(const s16x8*)&sA1[(l15*HID + kt*32 + 8*l4) ^ ((l15&7)<<3)];
                acc = mfma16(aA, fW2[kt], acc);
            }
            #pragma unroll
            for (int r = 0; r < 4; ++r){
                int row = 4*l4 + r, c = n0 + l15;
                float h = acc[r] + sb2[c];
                float sg = 1.0f / (1.0f + __expf(-h));
                sG2[(row*HID+c) ^ ((row&7)<<3)] = f2bf(sw3v[c] * (sg * (1.0f + h * (1.0f - sg))));
            }
        }
        __syncthreads();
        // ---- P3: g1 = (g2 @ W2) * d1 ----
        {
            f32x4 acc = {0.f,0.f,0.f,0.f};
            #pragma unroll
            for (int kt = 0; kt < 4; ++kt){
                s16x8 aG = *(const s16x8*)&sG2[(l15*HID + kt*32 + 8*l4) ^ ((l15&7)<<3)];
                acc = mfma16(aG, fW2T[kt], acc);
            }
            #pragma unroll
            for (int r = 0; r < 4; ++r){
                int row = 4*l4 + r, kc = n0 + l15;
                float g1v = acc[r] * bf2f(sD1[(row*HID+kc) ^ ((row&7)<<3)]);
                sG1[(row*HID+kc) ^ ((row&7)<<3)] = f2bf(g1v);
            }
        }
        __syncthreads();
        // ---- P4: grad = g1 @ W1 ; half/full kicks, write p to traj ----
        if (w < 4){
            f32x4 acc = {0.f,0.f,0.f,0.f};
            #pragma unroll
            for (int kt = 0; kt < 4; ++kt){
                s16x8 aG1 = *(const s16x8*)&sG1[(l15*HID + kt*32 + 8*l4) ^ ((l15&7)<<3)];
                acc = mfma16(aG1, fW1T[kt], acc);
            }
            #pragma unroll
            for (int r = 0; r < 4; ++r){
                int row = 4*l4 + r, dc = n0 + l15;
                float ph = sP[row*DIM+dc];
                float g = acc[r];
                float phn;
                if (t == 0){
                    phn = ph - 0.5f * dtv * g;          // initial half-kick; traj[0] already written
                } else {
                    out[(size_t)(b0+row)*TS + (size_t)t*128 + 64 + dc] = ph - 0.5f * dtv * g;
                    phn = ph - dtv * g;                 // combine the two half-kicks for next drift
                }
                sP[row*DIM+dc] = phn;
                sPb[(row*DIM+dc) ^ ((row&7)<<3)] = f2bf(phn);
            }
        }
        __syncthreads();
    }
}

extern "C" void kernel_launch(void* const* d_in, const int* in_sizes, int n_in,
                              void* d_out, int out_size, void* d_ws, size_t ws_size,
                              hipStream_t stream)
{
    const float* z  = (const float*)d_in[0];
    const float* L  = (const float*)d_in[1];
    const float* W1 = (const float*)d_in[2];
    const float* b1 = (const float*)d_in[3];
    const float* W2 = (const float*)d_in[4];
    const float* b2 = (const float*)d_in[5];
    const float* w3 = (const float*)d_in[6];
    // d_in[7] = Vb3: constant offset, vanishes in gradV
    const float* qW = (const float*)d_in[8];
    const float* qb = (const float*)d_in[9];
    const float* pW = (const float*)d_in[10];
    const float* pb = (const float*)d_in[11];
    const int* nsp  = (const int*)d_in[12];
    float* out = (float*)d_out;
    char* ws = (char*)d_ws;
    const int B = in_sizes[0] / DIM;

    k_prep<<<1, 256, 0, stream>>>(L, W1, W2, ws);
    k_enc<<<(B*128 + 255)/256, 256, 0, stream>>>(z, qW, qb, pW, pb, nsp, out, B);
    k_main<<<B/ROWS, TMAIN, 0, stream>>>(b1, b2, w3, nsp, ws, out);
}

// Round 2
// 222.101 us; speedup vs baseline: 1.6702x; 1.6702x over previous
//
#include <hip/hip_runtime.h>
#include <cstdint>
#include <cstddef>

#define HID 128
#define DIM 64
#define ROWS 16
#define TMAIN 512

typedef float f32x4 __attribute__((ext_vector_type(4)));
typedef short s16x8 __attribute__((ext_vector_type(8)));

__device__ __forceinline__ unsigned short f2bf(float x){
    union { float f; unsigned int u; } v; v.f = x;
    unsigned int r = v.u + 0x7FFFu + ((v.u >> 16) & 1u);
    return (unsigned short)(r >> 16);
}
__device__ __forceinline__ float bf2f(unsigned short b){
    union { unsigned int u; float f; } v; v.u = ((unsigned int)b) << 16;
    return v.f;
}

// workspace layout (bytes)
#define WS_MINV 0
#define WS_MHI  16384
#define WS_MLO  24576
#define WS_W1   32768
#define WS_W1T  49152
#define WS_W2   65536
#define WS_W2T  98304
// total 131072 bytes of d_ws used

// ---------------- kernel 1: invert M = L L^T + 0.01 I, prep bf16 weights ----------------
// Rewritten R1: conflict-free float4 column-slice Gauss-Jordan.
//   thread t owns cols c4=(t&31)*4..+3, rows r=(t>>5)+8j (j=0..7).
//   Per pivot step: phase A = all reads (b128 pivot row, broadcast f's, own rows),
//   barrier, phase B = all writes. 2 barriers/step, zero bank conflicts.
__global__ __launch_bounds__(256) void k_prep(
    const float* __restrict__ L, const float* __restrict__ W1,
    const float* __restrict__ W2, char* __restrict__ ws)
{
    __shared__ __align__(16) float aug[64][128];
    __shared__ float sL[64][65];       // +1 pad: L[c][k] -> bank (c+k)%32, conflict-free
    const int tid = threadIdx.x;

    // ---- bf16 weight prep (unchanged) ----
    unsigned short* w1b = (unsigned short*)(ws + WS_W1);
    unsigned short* w1t = (unsigned short*)(ws + WS_W1T);
    unsigned short* w2b = (unsigned short*)(ws + WS_W2);
    unsigned short* w2t = (unsigned short*)(ws + WS_W2T);
    for (int i = tid; i < HID*DIM; i += 256){
        float v = W1[i]; unsigned short b = f2bf(v);
        w1b[i] = b; int h = i >> 6, d = i & 63; w1t[d*HID + h] = b;
    }
    for (int i = tid; i < HID*HID; i += 256){
        float v = W2[i]; unsigned short b = f2bf(v);
        w2b[i] = b; int c2 = i >> 7, c1 = i & 127; w2t[c1*HID + c2] = b;
    }

    // ---- stage L into padded LDS ----
    for (int i = tid; i < 64*64; i += 256)
        sL[i >> 6][i & 63] = L[i];
    __syncthreads();

    // ---- build augmented [M | I], M = L L^T + 0.01 I ----
    for (int e = tid; e < 64*64; e += 256){
        int r = e >> 6, c = e & 63;
        float acc = (r == c) ? 0.01f : 0.0f;
        #pragma unroll 8
        for (int k = 0; k < 64; ++k) acc += sL[r][k] * sL[c][k];
        aug[r][c] = acc;
        aug[r][64+c] = (r == c) ? 1.0f : 0.0f;
    }

    // ---- Gauss-Jordan, no pivoting (M SPD, well-conditioned) ----
    const int c4 = (tid & 31) * 4;      // float4 column slice
    const int rb = tid >> 5;            // row base: rows rb, rb+8, ..., rb+56
    for (int k = 0; k < 64; ++k){
        __syncthreads();
        // phase A: reads only
        float pivinv = 1.0f / aug[k][k];
        f32x4 piv = *(const f32x4*)&aug[k][c4];
        piv *= pivinv;                            // normalized pivot row slice
        float f[8];
        f32x4 own[8];
        #pragma unroll
        for (int j = 0; j < 8; ++j){
            int r = rb + 8*j;
            f[j] = aug[r][k];
            own[j] = *(const f32x4*)&aug[r][c4];
        }
        __syncthreads();
        // phase B: writes only
        #pragma unroll
        for (int j = 0; j < 8; ++j){
            int r = rb + 8*j;
            f32x4 res = (r == k) ? piv : (own[j] - f[j] * piv);
            *(f32x4*)&aug[r][c4] = res;
        }
    }
    __syncthreads();

    // ---- write Minv f32 + hi/lo bf16 split ----
    float* minv = (float*)(ws + WS_MINV);
    unsigned short* mhi = (unsigned short*)(ws + WS_MHI);
    unsigned short* mlo = (unsigned short*)(ws + WS_MLO);
    for (int i = tid; i < 64*64; i += 256){
        float m = aug[i >> 6][64 + (i & 63)];
        minv[i] = m;
        unsigned short h = f2bf(m);
        mhi[i] = h;
        mlo[i] = f2bf(m - bf2f(h));
    }
}

// ---------------- kernel 2: encoder q0 = z qW^T + qb, p0 = z pW^T + pb -> traj[:,0,:] ----------------
__global__ __launch_bounds__(256) void k_enc(
    const float* __restrict__ z, const float* __restrict__ qW,
    const float* __restrict__ qb, const float* __restrict__ pW,
    const float* __restrict__ pb, const int* __restrict__ nsp,
    float* __restrict__ out, int B)
{
    const int g = blockIdx.x * 256 + threadIdx.x;
    if (g >= B * 128) return;
    const int b = g >> 7, dd = g & 127, d = dd & 63;
    const float* W = (dd < 64) ? qW : pW;
    const float* bias = (dd < 64) ? qb : pb;
    const float* zr = z + (size_t)b * 64;
    const float* wr = W + d * 64;
    float acc = bias[d];
    #pragma unroll 8
    for (int k = 0; k < 64; ++k) acc += zr[k] * wr[k];
    const int NS = *nsp;
    out[(size_t)b * ((size_t)(NS+1)*128) + dd] = acc;
}

// ---------------- kernel 3: 64 leapfrog steps, 16 rows/block, MFMA 16x16x32 bf16 ----------------
__device__ __forceinline__ f32x4 mfma16(s16x8 a, s16x8 b, f32x4 c){
    return __builtin_amdgcn_mfma_f32_16x16x32_bf16(a, b, c, 0, 0, 0);
}

__global__ __launch_bounds__(TMAIN) void k_main(
    const float* __restrict__ b1, const float* __restrict__ b2,
    const float* __restrict__ w3, const int* __restrict__ nsp,
    const char* __restrict__ ws, float* __restrict__ out)
{
    // ~30 KB static LDS; activation tiles XOR-swizzled: idx ^ ((row&7)<<3)
    __shared__ __align__(16) float sb1[HID], sb2[HID], sw3v[HID];
    __shared__ __align__(16) float sQ[ROWS*DIM], sP[ROWS*DIM];
    __shared__ __align__(16) unsigned short sQb[ROWS*DIM], sPb[ROWS*DIM];
    __shared__ __align__(16) unsigned short sA1[ROWS*HID], sD1[ROWS*HID];
    __shared__ __align__(16) unsigned short sG2[ROWS*HID], sG1[ROWS*HID];

    const int tid = threadIdx.x;
    const int w = tid >> 6;
    const int lane = tid & 63;
    const int l15 = lane & 15, l4 = lane >> 4;
    const int NS = *nsp;
    const float dtv = 1.0f / (float)NS;   // T_SPAN = (0,1)
    const int TS = (NS + 1) * 128;
    const int b0 = blockIdx.x * ROWS;
    const int n0 = w * 16;

    if (tid < HID){ sb1[tid] = b1[tid]; sb2[tid] = b2[tid]; sw3v[tid] = w3[tid]; }

    // load q0/p0 written by k_enc
    for (int e = tid; e < ROWS*128; e += TMAIN){
        int row = e >> 7, dd = e & 127;
        float v = out[(size_t)(b0+row)*TS + dd];
        if (dd < 64){ sQ[row*DIM+dd] = v; sQb[(row*DIM+dd) ^ ((row&7)<<3)] = f2bf(v); }
        else        { sP[row*DIM + (dd-64)] = v; }
    }

    // persistent weight B-fragments (BT[n][k] row-major -> lane reads BT[n0+l15][kt*32+8*l4 ..+8])
    const unsigned short* wsW1  = (const unsigned short*)(ws + WS_W1);
    const unsigned short* wsW1T = (const unsigned short*)(ws + WS_W1T);
    const unsigned short* wsW2  = (const unsigned short*)(ws + WS_W2);
    const unsigned short* wsW2T = (const unsigned short*)(ws + WS_W2T);
    const unsigned short* wsMhi = (const unsigned short*)(ws + WS_MHI);
    const unsigned short* wsMlo = (const unsigned short*)(ws + WS_MLO);

    s16x8 fW1[2], fW2[4], fW2T[4];
    s16x8 fW1T[4] = {}, fMhi[2] = {}, fMlo[2] = {};
    #pragma unroll
    for (int kt = 0; kt < 2; ++kt)
        fW1[kt] = *(const s16x8*)&wsW1[(n0+l15)*DIM + kt*32 + 8*l4];
    #pragma unroll
    for (int kt = 0; kt < 4; ++kt){
        fW2[kt]  = *(const s16x8*)&wsW2 [(n0+l15)*HID + kt*32 + 8*l4];
        fW2T[kt] = *(const s16x8*)&wsW2T[(n0+l15)*HID + kt*32 + 8*l4];
    }
    if (w < 4){
        #pragma unroll
        for (int kt = 0; kt < 4; ++kt)
            fW1T[kt] = *(const s16x8*)&wsW1T[(n0+l15)*HID + kt*32 + 8*l4];
        #pragma unroll
        for (int kt = 0; kt < 2; ++kt){
            fMhi[kt] = *(const s16x8*)&wsMhi[(n0+l15)*DIM + kt*32 + 8*l4];
            fMlo[kt] = *(const s16x8*)&wsMlo[(n0+l15)*DIM + kt*32 + 8*l4];
        }
    }
    __syncthreads();

    // t=0: gradV(q0) only (half-kick init). t>=1: drift + gradV + kick, write traj[t].
    for (int t = 0; t <= NS; ++t){
        // ---- phase Q: q += dt * Minv @ p_half ; write q to traj ----
        if (t > 0){
            if (w < 4){
                f32x4 acc = {0.f,0.f,0.f,0.f};
                #pragma unroll
                for (int kt = 0; kt < 2; ++kt){
                    s16x8 aP = *(const s16x8*)&sPb[(l15*DIM + kt*32 + 8*l4) ^ ((l15&7)<<3)];
                    acc = mfma16(aP, fMhi[kt], acc);
                    acc = mfma16(aP, fMlo[kt], acc);
                }
                #pragma unroll
                for (int r = 0; r < 4; ++r){
                    int row = 4*l4 + r, dc = n0 + l15;
                    float qn = sQ[row*DIM+dc] + dtv * acc[r];
                    sQ[row*DIM+dc] = qn;
                    sQb[(row*DIM+dc) ^ ((row&7)<<3)] = f2bf(qn);
                    out[(size_t)(b0+row)*TS + (size_t)t*128 + dc] = qn;
                }
            }
            __syncthreads();
        }
        // ---- P1: h1 = q@W1^T + b1 ; a1 = silu(h1), d1 = silu'(h1) ----
        {
            f32x4 acc = {0.f,0.f,0.f,0.f};
            #pragma unroll
            for (int kt = 0; kt < 2; ++kt){
                s16x8 aQ = *(const s16x8*)&sQb[(l15*DIM + kt*32 + 8*l4) ^ ((l15&7)<<3)];
                acc = mfma16(aQ, fW1[kt], acc);
            }
            #pragma unroll
            for (int r = 0; r < 4; ++r){
                int row = 4*l4 + r, c = n0 + l15;
                float h = acc[r] + sb1[c];
                float sg = 1.0f / (1.0f + __expf(-h));
                sA1[(row*HID+c) ^ ((row&7)<<3)] = f2bf(h * sg);
                sD1[(row*HID+c) ^ ((row&7)<<3)] = f2bf(sg * (1.0f + h * (1.0f - sg)));
            }
        }
        __syncthreads();
        // ---- P2: h2 = a1@W2^T + b2 ; g2 = w3 * silu'(h2) ----
        {
            f32x4 acc = {0.f,0.f,0.f,0.f};
            #pragma unroll
            for (int kt = 0; kt < 4; ++kt){
                s16x8 aA = *(const s16x8*)&sA1[(l15*HID + kt*32 + 8*l4) ^ ((l15&7)<<3)];
                acc = mfma16(aA, fW2[kt], acc);
            }
            #pragma unroll
            for (int r = 0; r < 4; ++r){
                int row = 4*l4 + r, c = n0 + l15;
                float h = acc[r] + sb2[c];
                float sg = 1.0f / (1.0f + __expf(-h));
                sG2[(row*HID+c) ^ ((row&7)<<3)] = f2bf(sw3v[c] * (sg * (1.0f + h * (1.0f - sg))));
            }
        }
        __syncthreads();
        // ---- P3: g1 = (g2 @ W2) * d1 ----
        {
            f32x4 acc = {0.f,0.f,0.f,0.f};
            #pragma unroll
            for (int kt = 0; kt < 4; ++kt){
                s16x8 aG = *(const s16x8*)&sG2[(l15*HID + kt*32 + 8*l4) ^ ((l15&7)<<3)];
                acc = mfma16(aG, fW2T[kt], acc);
            }
            #pragma unroll
            for (int r = 0; r < 4; ++r){
                int row = 4*l4 + r, kc = n0 + l15;
                float g1v = acc[r] * bf2f(sD1[(row*HID+kc) ^ ((row&7)<<3)]);
                sG1[(row*HID+kc) ^ ((row&7)<<3)] = f2bf(g1v);
            }
        }
        __syncthreads();
        // ---- P4: grad = g1 @ W1 ; half/full kicks, write p to traj ----
        if (w < 4){
            f32x4 acc = {0.f,0.f,0.f,0.f};
            #pragma unroll
            for (int kt = 0; kt < 4; ++kt){
                s16x8 aG1 = *(const s16x8*)&sG1[(l15*HID + kt*32 + 8*l4) ^ ((l15&7)<<3)];
                acc = mfma16(aG1, fW1T[kt], acc);
            }
            #pragma unroll
            for (int r = 0; r < 4; ++r){
                int row = 4*l4 + r, dc = n0 + l15;
                float ph = sP[row*DIM+dc];
                float g = acc[r];
                float phn;
                if (t == 0){
                    phn = ph - 0.5f * dtv * g;          // initial half-kick; traj[0] already written
                } else {
                    out[(size_t)(b0+row)*TS + (size_t)t*128 + 64 + dc] = ph - 0.5f * dtv * g;
                    phn = ph - dtv * g;                 // combine the two half-kicks for next drift
                }
                sP[row*DIM+dc] = phn;
                sPb[(row*DIM+dc) ^ ((row&7)<<3)] = f2bf(phn);
            }
        }
        __syncthreads();
    }
}

extern "C" void kernel_launch(void* const* d_in, const int* in_sizes, int n_in,
                              void* d_out, int out_size, void* d_ws, size_t ws_size,
                              hipStream_t stream)
{
    const float* z  = (const float*)d_in[0];
    const float* L  = (const float*)d_in[1];
    const float* W1 = (const float*)d_in[2];
    const float* b1 = (const float*)d_in[3];
    const float* W2 = (const float*)d_in[4];
    const float* b2 = (const float*)d_in[5];
    const float* w3 = (const float*)d_in[6];
    // d_in[7] = Vb3: constant offset, vanishes in gradV
    const float* qW = (const float*)d_in[8];
    const float* qb = (const float*)d_in[9];
    const float* pW = (const float*)d_in[10];
    const float* pb = (const float*)d_in[11];
    const int* nsp  = (const int*)d_in[12];
    float* out = (float*)d_out;
    char* ws = (char*)d_ws;
    const int B = in_sizes[0] / DIM;

    k_prep<<<1, 256, 0, stream>>>(L, W1, W2, ws);
    k_enc<<<(B*128 + 255)/256, 256, 0, stream>>>(z, qW, qb, pW, pb, nsp, out, B);
    k_main<<<B/ROWS, TMAIN, 0, stream>>>(b1, b2, w3, nsp, ws, out);
}

// Round 3
// 194.428 us; speedup vs baseline: 1.9079x; 1.1423x over previous
//
#include <hip/hip_runtime.h>
#include <hip/hip_bf16.h>
#include <cstdint>
#include <cstddef>

#define HID 128
#define DIM 64
#define ROWS 16
#define TMAIN 512

typedef float f32x4 __attribute__((ext_vector_type(4)));
typedef short s16x8 __attribute__((ext_vector_type(8)));
typedef unsigned int u32x2 __attribute__((ext_vector_type(2)));

__device__ __forceinline__ unsigned short f2bf(float x){
    union { float f; unsigned int u; } v; v.f = x;
    unsigned int r = v.u + 0x7FFFu + ((v.u >> 16) & 1u);
    return (unsigned short)(r >> 16);
}
__device__ __forceinline__ float bf2f(unsigned short b){
    union { unsigned int u; float f; } v; v.u = ((unsigned int)b) << 16;
    return v.f;
}
// packed f32x2 -> bf16x2 (RNE), single dword
__device__ __forceinline__ unsigned pk2(float a, float b){
    union { __hip_bfloat162 h; unsigned u; } cv;
    cv.h = __float22bfloat162_rn(make_float2(a, b));
    return cv.u;
}
__device__ __forceinline__ s16x8 mk8(unsigned a, unsigned b, unsigned c, unsigned d){
    union { s16x8 s; unsigned u[4]; } t; t.u[0]=a; t.u[1]=b; t.u[2]=c; t.u[3]=d; return t.s;
}
// load 8 consecutive f32 from global, convert to a bf16 MFMA fragment
__device__ __forceinline__ s16x8 ldfrag_f32(const float* base){
    f32x4 a = *(const f32x4*)base;
    f32x4 b = *(const f32x4*)(base + 4);
    return mk8(pk2(a[0],a[1]), pk2(a[2],a[3]), pk2(b[0],b[1]), pk2(b[2],b[3]));
}

// workspace layout (bytes)
#define WS_MINV 0
#define WS_MHI  16384
#define WS_MLO  24576
#define WS_W1   32768
#define WS_W1T  49152
#define WS_W2   65536
#define WS_W2T  98304
// total 131072 bytes of d_ws used

// ---------------- kernel 1: invert M = L L^T + 0.01 I, prep bf16 weights ----------------
// Conflict-free float4 column-slice Gauss-Jordan (R1).
__global__ __launch_bounds__(256) void k_prep(
    const float* __restrict__ L, const float* __restrict__ W1,
    const float* __restrict__ W2, char* __restrict__ ws)
{
    __shared__ __align__(16) float aug[64][128];
    __shared__ float sL[64][65];       // +1 pad: conflict-free
    const int tid = threadIdx.x;

    unsigned short* w1b = (unsigned short*)(ws + WS_W1);
    unsigned short* w1t = (unsigned short*)(ws + WS_W1T);
    unsigned short* w2b = (unsigned short*)(ws + WS_W2);
    unsigned short* w2t = (unsigned short*)(ws + WS_W2T);
    for (int i = tid; i < HID*DIM; i += 256){
        float v = W1[i]; unsigned short b = f2bf(v);
        w1b[i] = b; int h = i >> 6, d = i & 63; w1t[d*HID + h] = b;
    }
    for (int i = tid; i < HID*HID; i += 256){
        float v = W2[i]; unsigned short b = f2bf(v);
        w2b[i] = b; int c2 = i >> 7, c1 = i & 127; w2t[c1*HID + c2] = b;
    }

    for (int i = tid; i < 64*64; i += 256)
        sL[i >> 6][i & 63] = L[i];
    __syncthreads();

    for (int e = tid; e < 64*64; e += 256){
        int r = e >> 6, c = e & 63;
        float acc = (r == c) ? 0.01f : 0.0f;
        #pragma unroll 8
        for (int k = 0; k < 64; ++k) acc += sL[r][k] * sL[c][k];
        aug[r][c] = acc;
        aug[r][64+c] = (r == c) ? 1.0f : 0.0f;
    }

    const int c4 = (tid & 31) * 4;
    const int rb = tid >> 5;
    for (int k = 0; k < 64; ++k){
        __syncthreads();
        float pivinv = 1.0f / aug[k][k];
        f32x4 piv = *(const f32x4*)&aug[k][c4];
        piv *= pivinv;
        float f[8];
        f32x4 own[8];
        #pragma unroll
        for (int j = 0; j < 8; ++j){
            int r = rb + 8*j;
            f[j] = aug[r][k];
            own[j] = *(const f32x4*)&aug[r][c4];
        }
        __syncthreads();
        #pragma unroll
        for (int j = 0; j < 8; ++j){
            int r = rb + 8*j;
            f32x4 res = (r == k) ? piv : (own[j] - f[j] * piv);
            *(f32x4*)&aug[r][c4] = res;
        }
    }
    __syncthreads();

    float* minv = (float*)(ws + WS_MINV);
    unsigned short* mhi = (unsigned short*)(ws + WS_MHI);
    unsigned short* mlo = (unsigned short*)(ws + WS_MLO);
    for (int i = tid; i < 64*64; i += 256){
        float m = aug[i >> 6][64 + (i & 63)];
        minv[i] = m;
        unsigned short h = f2bf(m);
        mhi[i] = h;
        mlo[i] = f2bf(m - bf2f(h));
    }
}

// ---------------- kernel 2: encoder + 64 leapfrog steps, swapped-operand MFMA ----------------
// D = W (A-frag, registers) x X^T (B-frag = contiguous b128 read of X[batch][feat]).
// C/D layout: col = lane&15 = batch row, row = 4*(lane>>4)+reg = feature -> each lane
// holds 4 CONSECUTIVE features of one batch row: packed cvt_pk + ds_write_b64 epilogues,
// f32x4 master updates, dwordx4 traj stores. 16B-granule XOR swizzle on all tiles.
__device__ __forceinline__ f32x4 mfma16(s16x8 a, s16x8 b, f32x4 c){
    return __builtin_amdgcn_mfma_f32_16x16x32_bf16(a, b, c, 0, 0, 0);
}

__global__ __launch_bounds__(TMAIN) void k_main(
    const float* __restrict__ z, const float* __restrict__ qW,
    const float* __restrict__ qb, const float* __restrict__ pW,
    const float* __restrict__ pb, const float* __restrict__ b1,
    const float* __restrict__ b2, const float* __restrict__ w3,
    const int* __restrict__ nsp, const char* __restrict__ ws,
    float* __restrict__ out)
{
    // tiles: f32 [16][64] stride 256B; bf16 [16][64] stride 128B; bf16 [16][128] stride 256B;
    // f32 [16][128] stride 512B. All swizzled: byte_col ^ ((row&7)<<4).
    __shared__ __align__(16) char sQ_[ROWS*256], sP_[ROWS*256];
    __shared__ __align__(16) char sQb_[ROWS*128], sPb_[ROWS*128];
    __shared__ __align__(16) char sA1_[ROWS*256], sG2_[ROWS*256], sG1_[ROWS*256];
    __shared__ __align__(16) char sD1_[ROWS*512];

    const int tid = threadIdx.x;
    const int w = tid >> 6, lane = tid & 63;
    const int l15 = lane & 15, l4 = lane >> 4;
    const int sw = (l15 & 7) << 4;
    const int m0 = w * 16;          // feature tile base, P1-P3 (0..112)
    const int wq = w & 3;
    const int mq = wq * 16;         // dim tile base, Q/P4/enc (0..48)
    const int NS = *nsp;
    const float dtv = 1.0f / (float)NS;   // T_SPAN = (0,1)
    const int TS = (NS + 1) * 128;
    const int b0 = blockIdx.x * ROWS;

    // ---- persistent weight A-fragments (bit-identical loads to R1's B-frags) ----
    const unsigned short* wsW1  = (const unsigned short*)(ws + WS_W1);
    const unsigned short* wsW1T = (const unsigned short*)(ws + WS_W1T);
    const unsigned short* wsW2  = (const unsigned short*)(ws + WS_W2);
    const unsigned short* wsW2T = (const unsigned short*)(ws + WS_W2T);
    const unsigned short* wsMhi = (const unsigned short*)(ws + WS_MHI);
    const unsigned short* wsMlo = (const unsigned short*)(ws + WS_MLO);

    s16x8 fW1[2], fW2[4], fW2T[4];
    s16x8 fW1T[4] = {}, fMhi[2] = {}, fMlo[2] = {};
    #pragma unroll
    for (int kt = 0; kt < 2; ++kt)
        fW1[kt] = *(const s16x8*)&wsW1[(m0+l15)*DIM + kt*32 + 8*l4];
    #pragma unroll
    for (int kt = 0; kt < 4; ++kt){
        fW2[kt]  = *(const s16x8*)&wsW2 [(m0+l15)*HID + kt*32 + 8*l4];
        fW2T[kt] = *(const s16x8*)&wsW2T[(m0+l15)*HID + kt*32 + 8*l4];
    }
    if (w < 4){
        #pragma unroll
        for (int kt = 0; kt < 4; ++kt)
            fW1T[kt] = *(const s16x8*)&wsW1T[(mq+l15)*HID + kt*32 + 8*l4];
        #pragma unroll
        for (int kt = 0; kt < 2; ++kt){
            fMhi[kt] = *(const s16x8*)&wsMhi[(mq+l15)*DIM + kt*32 + 8*l4];
            fMlo[kt] = *(const s16x8*)&wsMlo[(mq+l15)*DIM + kt*32 + 8*l4];
        }
    }

    // biases / w3 in registers (uniform over l15)
    const f32x4 bb1 = *(const f32x4*)&b1[m0 + 4*l4];
    const f32x4 bb2 = *(const f32x4*)&b2[m0 + 4*l4];
    const f32x4 bw3 = *(const f32x4*)&w3[m0 + 4*l4];

    // ---- encoder: q0/p0 = z @ {q,p}W^T + bias ; all 8 waves (4 q-tiles + 4 p-tiles) ----
    {
        const float* zr = z + (size_t)(b0 + l15) * DIM;
        s16x8 bz0 = ldfrag_f32(zr + 8*l4);
        s16x8 bz1 = ldfrag_f32(zr + 32 + 8*l4);
        const float* eW = (w < 4) ? qW : pW;
        const float* eb = (w < 4) ? qb : pb;
        const float* wr = eW + (size_t)(mq + l15) * DIM;
        s16x8 fE0 = ldfrag_f32(wr + 8*l4);
        s16x8 fE1 = ldfrag_f32(wr + 32 + 8*l4);
        f32x4 acc = {0.f,0.f,0.f,0.f};
        acc = mfma16(fE0, bz0, acc);
        acc = mfma16(fE1, bz1, acc);
        f32x4 be = *(const f32x4*)&eb[mq + 4*l4];
        f32x4 v = acc + be;
        char* sM  = (w < 4) ? sQ_ : sP_;
        char* sMb = (w < 4) ? sQb_ : sPb_;
        *(f32x4*)(sM + l15*256 + ((64*wq + 16*l4) ^ sw)) = v;
        u32x2 pr; pr[0] = pk2(v[0],v[1]); pr[1] = pk2(v[2],v[3]);
        *(u32x2*)(sMb + l15*128 + ((32*wq + 8*l4) ^ sw)) = pr;
        const int ofs = (w < 4) ? (mq + 4*l4) : (64 + mq + 4*l4);
        *(f32x4*)(out + (size_t)(b0 + l15) * TS + ofs) = v;
    }
    __syncthreads();

    // t=0: gradV(q0) only (half-kick init). t>=1: drift + gradV + kick, write traj[t].
    for (int t = 0; t <= NS; ++t){
        // ---- Q: q += dt * Minv @ p_half (hi/lo split) ----
        if (t > 0){
            if (w < 4){
                f32x4 acc = {0.f,0.f,0.f,0.f};
                #pragma unroll
                for (int kt = 0; kt < 2; ++kt){
                    s16x8 bp = *(const s16x8*)(sPb_ + l15*128 + ((64*kt + 16*l4) ^ sw));
                    acc = mfma16(fMhi[kt], bp, acc);
                    acc = mfma16(fMlo[kt], bp, acc);
                }
                f32x4* qp = (f32x4*)(sQ_ + l15*256 + ((64*wq + 16*l4) ^ sw));
                f32x4 qv = *qp;
                #pragma unroll
                for (int r = 0; r < 4; ++r) qv[r] += dtv * acc[r];
                *qp = qv;
                u32x2 pr; pr[0] = pk2(qv[0],qv[1]); pr[1] = pk2(qv[2],qv[3]);
                *(u32x2*)(sQb_ + l15*128 + ((32*wq + 8*l4) ^ sw)) = pr;
                *(f32x4*)(out + (size_t)(b0+l15)*TS + (size_t)t*128 + mq + 4*l4) = qv;
            }
            __syncthreads();
        }
        // ---- P1: h1 = q@W1^T + b1 ; a1 = silu (bf16), d1 = silu' (f32) ----
        {
            f32x4 acc = {0.f,0.f,0.f,0.f};
            #pragma unroll
            for (int kt = 0; kt < 2; ++kt){
                s16x8 bq = *(const s16x8*)(sQb_ + l15*128 + ((64*kt + 16*l4) ^ sw));
                acc = mfma16(fW1[kt], bq, acc);
            }
            f32x4 si, dv;
            #pragma unroll
            for (int r = 0; r < 4; ++r){
                float h = acc[r] + bb1[r];
                float sg = 1.0f / (1.0f + __expf(-h));
                float s = h * sg;
                si[r] = s;
                dv[r] = sg + s * (1.0f - sg);
            }
            u32x2 pr; pr[0] = pk2(si[0],si[1]); pr[1] = pk2(si[2],si[3]);
            *(u32x2*)(sA1_ + l15*256 + ((2*m0 + 8*l4) ^ sw)) = pr;
            *(f32x4*)(sD1_ + l15*512 + ((4*m0 + 16*l4) ^ sw)) = dv;
        }
        __syncthreads();
        // ---- P2: h2 = a1@W2^T + b2 ; g2 = w3 * silu'(h2) ----
        {
            f32x4 acc = {0.f,0.f,0.f,0.f};
            #pragma unroll
            for (int kt = 0; kt < 4; ++kt){
                s16x8 ba = *(const s16x8*)(sA1_ + l15*256 + ((64*kt + 16*l4) ^ sw));
                acc = mfma16(fW2[kt], ba, acc);
            }
            f32x4 g2;
            #pragma unroll
            for (int r = 0; r < 4; ++r){
                float h = acc[r] + bb2[r];
                float sg = 1.0f / (1.0f + __expf(-h));
                g2[r] = bw3[r] * (sg * (1.0f + h * (1.0f - sg)));
            }
            u32x2 pr; pr[0] = pk2(g2[0],g2[1]); pr[1] = pk2(g2[2],g2[3]);
            *(u32x2*)(sG2_ + l15*256 + ((2*m0 + 8*l4) ^ sw)) = pr;
        }
        __syncthreads();
        // ---- P3: g1 = (g2 @ W2) * d1 ----
        {
            f32x4 acc = {0.f,0.f,0.f,0.f};
            #pragma unroll
            for (int kt = 0; kt < 4; ++kt){
                s16x8 bg = *(const s16x8*)(sG2_ + l15*256 + ((64*kt + 16*l4) ^ sw));
                acc = mfma16(fW2T[kt], bg, acc);
            }
            f32x4 dv = *(const f32x4*)(sD1_ + l15*512 + ((4*m0 + 16*l4) ^ sw));
            f32x4 g1 = acc * dv;
            u32x2 pr; pr[0] = pk2(g1[0],g1[1]); pr[1] = pk2(g1[2],g1[3]);
            *(u32x2*)(sG1_ + l15*256 + ((2*m0 + 8*l4) ^ sw)) = pr;
        }
        __syncthreads();
        // ---- P4: grad = g1 @ W1 ; half/full kicks, write p to traj ----
        if (w < 4){
            f32x4 acc = {0.f,0.f,0.f,0.f};
            #pragma unroll
            for (int kt = 0; kt < 4; ++kt){
                s16x8 bg = *(const s16x8*)(sG1_ + l15*256 + ((64*kt + 16*l4) ^ sw));
                acc = mfma16(fW1T[kt], bg, acc);
            }
            f32x4* pp = (f32x4*)(sP_ + l15*256 + ((64*wq + 16*l4) ^ sw));
            f32x4 pv = *pp;
            if (t == 0){
                #pragma unroll
                for (int r = 0; r < 4; ++r) pv[r] -= 0.5f * dtv * acc[r];
            } else {
                f32x4 ph;
                #pragma unroll
                for (int r = 0; r < 4; ++r){
                    ph[r] = pv[r] - 0.5f * dtv * acc[r];   // p at step t (output)
                    pv[r] -= dtv * acc[r];                  // combined kicks for next drift
                }
                *(f32x4*)(out + (size_t)(b0+l15)*TS + (size_t)t*128 + 64 + mq + 4*l4) = ph;
            }
            *pp = pv;
            u32x2 pr; pr[0] = pk2(pv[0],pv[1]); pr[1] = pk2(pv[2],pv[3]);
            *(u32x2*)(sPb_ + l15*128 + ((32*wq + 8*l4) ^ sw)) = pr;
        }
        __syncthreads();
    }
}

extern "C" void kernel_launch(void* const* d_in, const int* in_sizes, int n_in,
                              void* d_out, int out_size, void* d_ws, size_t ws_size,
                              hipStream_t stream)
{
    const float* z  = (const float*)d_in[0];
    const float* L  = (const float*)d_in[1];
    const float* W1 = (const float*)d_in[2];
    const float* b1 = (const float*)d_in[3];
    const float* W2 = (const float*)d_in[4];
    const float* b2 = (const float*)d_in[5];
    const float* w3 = (const float*)d_in[6];
    // d_in[7] = Vb3: constant offset, vanishes in gradV
    const float* qW = (const float*)d_in[8];
    const float* qb = (const float*)d_in[9];
    const float* pW = (const float*)d_in[10];
    const float* pb = (const float*)d_in[11];
    const int* nsp  = (const int*)d_in[12];
    float* out = (float*)d_out;
    char* ws = (char*)d_ws;
    const int B = in_sizes[0] / DIM;

    k_prep<<<1, 256, 0, stream>>>(L, W1, W2, ws);
    k_main<<<B/ROWS, TMAIN, 0, stream>>>(z, qW, qb, pW, pb, b1, b2, w3, nsp, ws, out);
}